// Round 1
// baseline (3838.346 us; speedup 1.0000x reference)
//
#include <hip/hip_runtime.h>
#include <math.h>

#define EMB 256
#define VOCAB 50000
#define TROWS 101
#define NLB 32   // lstm launch blocks; 4 same-XCD workers elected at runtime
#define NW 4     // lstm worker workgroups

__device__ __forceinline__ float sigf(float x) { return 1.0f / (1.0f + expf(-x)); }

// ---------------------------------------------------------------------------
// K1: conv tower (8 shared-weight conv3x3 + batchnorm stages), single block.
// ---------------------------------------------------------------------------
__global__ __launch_bounds__(384) void k_conv(
    const float* __restrict__ board, const float* __restrict__ conv_w,
    const float* __restrict__ conv_b, const float* __restrict__ bn_g,
    const float* __restrict__ bn_b, const float* __restrict__ p,
    float* __restrict__ d1g) {
  __shared__ float xa[361], xb[361];
  __shared__ float wred[6];
  __shared__ float mu_s, var_s;
  const int tid = threadIdx.x;
  const bool act = tid < 361;
  const int i = tid / 19, j = tid % 19;
  float cw[9];
#pragma unroll
  for (int q = 0; q < 9; q++) cw[q] = conv_w[q];
  const float cb = conv_b[0], gam = bn_g[0], bet = bn_b[0];
  if (act) xa[tid] = board[tid];
  __syncthreads();

  float d2 = 0.f;
  float* cur = xa;
  float* nxt = xb;
  for (int stage = 0; stage < 8; stage++) {
    float y = 0.f;
    if (act) {
#pragma unroll
      for (int di = 0; di < 3; di++) {
#pragma unroll
        for (int dj = 0; dj < 3; dj++) {
          int ii = i + di - 1, jj = j + dj - 1;
          float xv = (ii >= 0 && ii < 19 && jj >= 0 && jj < 19) ? cur[ii * 19 + jj] : 0.f;
          y += cw[di * 3 + dj] * xv;
        }
      }
      y += cb;
    }
    float s = act ? y : 0.f;
#pragma unroll
    for (int o = 32; o > 0; o >>= 1) s += __shfl_xor(s, o);
    if ((tid & 63) == 0) wred[tid >> 6] = s;
    __syncthreads();
    if (tid == 0) {
      float tt = 0.f;
      for (int q = 0; q < 6; q++) tt += wred[q];
      mu_s = tt / 361.f;
    }
    __syncthreads();
    const float mu = mu_s;
    float d = act ? (y - mu) : 0.f;
    s = d * d;
#pragma unroll
    for (int o = 32; o > 0; o >>= 1) s += __shfl_xor(s, o);
    if ((tid & 63) == 0) wred[tid >> 6] = s;
    __syncthreads();
    if (tid == 0) {
      float tt = 0.f;
      for (int q = 0; q < 6; q++) tt += wred[q];
      var_s = tt / 361.f;
    }
    __syncthreads();
    const float xn = gam * (y - mu) * (1.0f / sqrtf(var_s + 1e-5f)) + bet;

    float v;
    if (stage == 0) {
      v = fmaxf(p[0] * xn, 0.f);
      d2 = v;
    } else if (stage == 7) {
      v = fmaxf(xn, 0.f);
    } else if (stage & 1) {
      v = fmaxf(p[stage] * xn, 0.f);
    } else {
      v = fmaxf(p[stage] * xn + d2, 0.f);
      d2 = v;
    }
    if (act) nxt[tid] = v;
    __syncthreads();
    float* tmp = cur; cur = nxt; nxt = tmp;
  }
  if (act) d1g[tid] = cur[tid];
}

// ---------------------------------------------------------------------------
// K2: feat = W_lin @ d1 + b_lin.
// ---------------------------------------------------------------------------
__global__ __launch_bounds__(256) void k_feat(
    const float* __restrict__ W_lin, const float* __restrict__ b_lin,
    const float* __restrict__ d1g, float* __restrict__ feat) {
  const int wid = threadIdx.x >> 6, lane = threadIdx.x & 63;
  const int rbase = blockIdx.x * 16 + wid * 4;
  for (int rr = 0; rr < 4; rr++) {
    const int r = rbase + rr;
    const float* wrow = W_lin + r * 361;
    float s = 0.f;
    for (int k = lane; k < 361; k += 64) s += wrow[k] * d1g[k];
#pragma unroll
    for (int o = 32; o > 0; o >>= 1) s += __shfl_xor(s, o);
    if (lane == 0) feat[r] = s + b_lin[r];
  }
}

// ---------------------------------------------------------------------------
// K3: LSTM chain. 32 blocks launched; 4 workers ELECTED on one measured XCD
// (pigeonhole: 32 blocks over 8 XCDs guarantees some XCD holds >= 4).
// Workers then exchange h slices through their SHARED per-XCD L2:
//   producer: plain 8B packet store (write-through L1 -> shared L2)
//   consumer: inline-asm global_load_dwordx2 sc0 (L1-bypass, L2-coherent)
// Same self-validating {tag,payload} double-buffered protocol as before.
// Fallback: after 256 spins a consumer re-polls at agent scope (MALL), so a
// wrong placement model degrades to slow-but-correct instead of hanging.
// ---------------------------------------------------------------------------
__global__ __launch_bounds__(512) void k_lstm(
    const float* __restrict__ W_ih, const float* __restrict__ b_ih,
    const float* __restrict__ W_hh, const float* __restrict__ b_hh,
    const float* __restrict__ feat, float* __restrict__ h_all,
    unsigned long long* hcomm, unsigned long long* xtab) {
  __shared__ float h_lds[EMB];
  __shared__ float gbuf[EMB];
  __shared__ int sxcd[NLB];
  const int tid = threadIdx.x;

  // ---- same-XCD election (once, ~µs) ----
  if (tid == 0) {
    // s_getreg hwreg(HW_REG_XCC_ID=20, offset 0, size 32) -> simm 63508
    unsigned xcc = __builtin_amdgcn_s_getreg(63508) & 7u;
    __hip_atomic_store(&xtab[blockIdx.x],
                       0xE1EC000000000000ULL | (unsigned long long)xcc,
                       __ATOMIC_RELAXED, __HIP_MEMORY_SCOPE_AGENT);
  }
  if (tid < NLB) {
    const unsigned long long* slot = &xtab[tid];
    unsigned long long u;
    while (1) {
      u = __hip_atomic_load(slot, __ATOMIC_RELAXED, __HIP_MEMORY_SCOPE_AGENT);
      if ((unsigned)(u >> 32) == 0xE1EC0000u) break;
      __builtin_amdgcn_s_sleep(2);
    }
    sxcd[tid] = (int)((unsigned)u & 7u);
  }
  __syncthreads();
  int target = -1;
  for (int x = 0; x < 8; x++) {
    int n = 0;
    for (int b = 0; b < NLB; b++) n += (sxcd[b] == x);
    if (n >= NW) { target = x; break; }
  }
  int rank = -1, seen = 0;
  for (int b = 0; b < NLB; b++) {
    if (sxcd[b] == target) {
      if (b == (int)blockIdx.x) rank = seen;
      seen++;
    }
  }
  if (rank < 0 || rank >= NW) return;  // non-worker block
  const int g = rank;                  // worker slice index, all on one XCD

  // ---- LSTM body (identical math to previous version) ----
  const int r = tid >> 1, s = tid & 1;
  const int R = ((r >> 6) << 8) + g * 64 + (r & 63);
  const float bsum = b_ih[R] + b_hh[R];

  float4 w4[32];
  {
    const float4* wih = (const float4*)(W_ih + R * EMB + s * 128);
#pragma unroll
    for (int q = 0; q < 32; q++) w4[q] = wih[q];
  }
  if (tid < EMB) h_lds[tid] = feat[tid];  // x_in for step 0
  float c = 0.f;
  __syncthreads();

  for (int t = 0; t <= 100; t++) {
    // gates: 128-wide dot per thread + pair reduce
    const float4* h4 = ((const float4*)h_lds) + s * 32;
    float acc = 0.f;
#pragma unroll
    for (int q = 0; q < 32; q++) {
      float4 hv = h4[q], wv = w4[q];
      acc += wv.x * hv.x + wv.y * hv.y + wv.z * hv.z + wv.w * hv.w;
    }
    acc += __shfl_xor(acc, 1);
    if (s == 0) gbuf[r] = acc + bsum;
    __syncthreads();  // B1: gbuf ready; matvec reads of h_lds done

    if (tid < 64) {
      float gi = gbuf[tid], gf = gbuf[64 + tid], gg = gbuf[128 + tid], go = gbuf[192 + tid];
      c = sigf(gf) * c + sigf(gi) * tanhf(gg);
      float h = sigf(go) * tanhf(c);
      const int j = g * 64 + tid;
      h_all[t * EMB + j] = h;  // for k_dec (kernel-boundary visibility)
      if (t < 100) {
        unsigned long long pkt =
            ((unsigned long long)(unsigned)(t + 1) << 32) | (unsigned long long)__float_as_uint(h);
        // plain store: write-through L1 into the XCD-shared L2 (workers co-located)
        __hip_atomic_store(&hcomm[(t & 1) * EMB + j], pkt,
                           __ATOMIC_RELAXED, __HIP_MEMORY_SCOPE_WORKGROUP);
      }
    }
    if (t < 100) {
      if (tid < EMB) {
        const unsigned long long* slot = &hcomm[(t & 1) * EMB + tid];
        unsigned long long u;
        int spins = 0;
        while (1) {
          if (spins < 256) {
            // L1-bypass, L2-coherent poll (same-XCD fast path)
            asm volatile("global_load_dwordx2 %0, %1, off sc0\n\ts_waitcnt vmcnt(0)"
                         : "=&v"(u) : "v"(slot) : "memory");
          } else {
            // defensive fallback: device-scope (MALL) poll
            u = __hip_atomic_load(slot, __ATOMIC_RELAXED, __HIP_MEMORY_SCOPE_AGENT);
          }
          if ((unsigned)(u >> 32) == (unsigned)(t + 1)) break;
          spins++;
          __builtin_amdgcn_s_sleep(1);
        }
        h_lds[tid] = __uint_as_float((unsigned)u);
      }
      __syncthreads();  // B2: h_lds(t+1) ready for everyone
    }
    if (t == 0) {  // switch to W_sum = W_ih + W_hh for steps >= 1
      const float4* whh = (const float4*)(W_hh + R * EMB + s * 128);
#pragma unroll
      for (int q = 0; q < 32; q++) {
        float4 a = whh[q];
        w4[q].x += a.x; w4[q].y += a.y; w4[q].z += a.z; w4[q].w += a.w;
      }
    }
  }
}

// ---------------------------------------------------------------------------
// K4: decode GEMM  out[t][v] = relu(W_dec[v,:] . h_all[t,:] + b_dec[v])
// 391 blocks x 256 thr. Per block: Vtile=128, all 101 t.
// ---------------------------------------------------------------------------
__global__ __launch_bounds__(256) void k_dec(
    const float* __restrict__ W_dec, const float* __restrict__ b_dec,
    const float* __restrict__ h_all, float* __restrict__ out) {
  __shared__ float4 ldsH[104 * 32];  // 104 t-rows x 32 float4 (K-chunk 128)
  const int tid = threadIdx.x;
  const int vp = tid & 63, tg = tid >> 6;
  const int v0 = blockIdx.x * 128 + vp;
  const int v1 = v0 + 64;
  const int r0 = v0 < VOCAB ? v0 : VOCAB - 1;
  const int r1 = v1 < VOCAB ? v1 : VOCAB - 1;
  const float4* wr0 = (const float4*)(W_dec + r0 * EMB);
  const float4* wr1 = (const float4*)(W_dec + r1 * EMB);
  const float4* h4g = (const float4*)h_all;

  float acc0[26], acc1[26];
#pragma unroll
  for (int q = 0; q < 26; q++) { acc0[q] = 0.f; acc1[q] = 0.f; }

  for (int ch = 0; ch < 2; ch++) {
    if (ch) __syncthreads();  // protect LDS reuse
    for (int f = tid; f < TROWS * 32; f += 256) {
      int t = f >> 5, cc = f & 31;
      ldsH[t * 32 + cc] = h4g[t * 64 + ch * 32 + cc];
    }
    __syncthreads();

    for (int k8 = 0; k8 < 4; k8++) {
      float4 wa[8], wb[8];
#pragma unroll
      for (int jj = 0; jj < 8; jj++) {
        wa[jj] = wr0[ch * 32 + k8 * 8 + jj];
        wb[jj] = wr1[ch * 32 + k8 * 8 + jj];
      }
#pragma unroll
      for (int q = 0; q < 26; q++) {
        const float4* hrow = &ldsH[(tg * 26 + q) * 32 + k8 * 8];
#pragma unroll
        for (int jj = 0; jj < 8; jj++) {
          float4 h = hrow[jj];
          acc0[q] += wa[jj].x * h.x + wa[jj].y * h.y + wa[jj].z * h.z + wa[jj].w * h.w;
          acc1[q] += wb[jj].x * h.x + wb[jj].y * h.y + wb[jj].z * h.z + wb[jj].w * h.w;
        }
      }
    }
  }
  const float bd0 = b_dec[r0], bd1 = b_dec[r1];
#pragma unroll
  for (int q = 0; q < 26; q++) {
    int t = tg * 26 + q;
    if (t < TROWS) {
      if (v0 < VOCAB) out[t * VOCAB + v0] = fmaxf(acc0[q] + bd0, 0.f);
      if (v1 < VOCAB) out[t * VOCAB + v1] = fmaxf(acc1[q] + bd1, 0.f);
    }
  }
}

// ---------------------------------------------------------------------------
extern "C" void kernel_launch(void* const* d_in, const int* in_sizes, int n_in,
                              void* d_out, int out_size, void* d_ws, size_t ws_size,
                              hipStream_t stream) {
  const float* board  = (const float*)d_in[0];
  const float* conv_w = (const float*)d_in[1];
  const float* conv_b = (const float*)d_in[2];
  const float* bn_g   = (const float*)d_in[3];
  const float* bn_b   = (const float*)d_in[4];
  const float* p      = (const float*)d_in[5];
  const float* W_lin  = (const float*)d_in[6];
  const float* b_lin  = (const float*)d_in[7];
  const float* W_ih   = (const float*)d_in[8];
  const float* b_ih   = (const float*)d_in[9];
  const float* W_hh   = (const float*)d_in[10];
  const float* b_hh   = (const float*)d_in[11];
  const float* W_dec  = (const float*)d_in[12];
  const float* b_dec  = (const float*)d_in[13];

  float* wsf   = (float*)d_ws;
  float* feat  = wsf;                        // 256 floats
  float* d1g   = wsf + 256;                  // 384 slot (361 used)
  float* h_all = wsf + 640;                  // 101*256 floats
  unsigned long long* hcomm =
      (unsigned long long*)(wsf + 640 + 104 * 256);  // 512 u64 (8B aligned)
  unsigned long long* xtab = hcomm + 512;            // 32 u64 election table
  // hcomm/xtab need no init: poison 0xAAAAAAAA never matches tag values
  // (t+1 in [1,100] for hcomm; 0xE1EC0000 for xtab).

  k_conv<<<1, 384, 0, stream>>>(board, conv_w, conv_b, bn_g, bn_b, p, d1g);
  k_feat<<<16, 256, 0, stream>>>(W_lin, b_lin, d1g, feat);
  k_lstm<<<NLB, 512, 0, stream>>>(W_ih, b_ih, W_hh, b_hh, feat, h_all, hcomm, xtab);
  k_dec<<<(VOCAB + 127) / 128, 256, 0, stream>>>(W_dec, b_dec, h_all, (float*)d_out);
}

// Round 2
// 935.839 us; speedup vs baseline: 4.1015x; 4.1015x over previous
//
#include <hip/hip_runtime.h>
#include <math.h>

#define EMB 256
#define VOCAB 50000
#define TROWS 101
#define NWG 4           // LSTM workgroups (4 x 512 threads) — proven layout

__device__ __forceinline__ float sigf(float x) { return 1.0f / (1.0f + expf(-x)); }

// ---------------------------------------------------------------------------
// K1: conv tower (8 shared-weight conv3x3 + batchnorm stages), single block.
// ---------------------------------------------------------------------------
__global__ __launch_bounds__(384) void k_conv(
    const float* __restrict__ board, const float* __restrict__ conv_w,
    const float* __restrict__ conv_b, const float* __restrict__ bn_g,
    const float* __restrict__ bn_b, const float* __restrict__ p,
    float* __restrict__ d1g) {
  __shared__ float xa[361], xb[361];
  __shared__ float wred[6];
  __shared__ float mu_s, var_s;
  const int tid = threadIdx.x;
  const bool act = tid < 361;
  const int i = tid / 19, j = tid % 19;
  float cw[9];
#pragma unroll
  for (int q = 0; q < 9; q++) cw[q] = conv_w[q];
  const float cb = conv_b[0], gam = bn_g[0], bet = bn_b[0];
  if (act) xa[tid] = board[tid];
  __syncthreads();

  float d2 = 0.f;
  float* cur = xa;
  float* nxt = xb;
  for (int stage = 0; stage < 8; stage++) {
    float y = 0.f;
    if (act) {
#pragma unroll
      for (int di = 0; di < 3; di++) {
#pragma unroll
        for (int dj = 0; dj < 3; dj++) {
          int ii = i + di - 1, jj = j + dj - 1;
          float xv = (ii >= 0 && ii < 19 && jj >= 0 && jj < 19) ? cur[ii * 19 + jj] : 0.f;
          y += cw[di * 3 + dj] * xv;
        }
      }
      y += cb;
    }
    float s = act ? y : 0.f;
#pragma unroll
    for (int o = 32; o > 0; o >>= 1) s += __shfl_xor(s, o);
    if ((tid & 63) == 0) wred[tid >> 6] = s;
    __syncthreads();
    if (tid == 0) {
      float tt = 0.f;
      for (int q = 0; q < 6; q++) tt += wred[q];
      mu_s = tt / 361.f;
    }
    __syncthreads();
    const float mu = mu_s;
    float d = act ? (y - mu) : 0.f;
    s = d * d;
#pragma unroll
    for (int o = 32; o > 0; o >>= 1) s += __shfl_xor(s, o);
    if ((tid & 63) == 0) wred[tid >> 6] = s;
    __syncthreads();
    if (tid == 0) {
      float tt = 0.f;
      for (int q = 0; q < 6; q++) tt += wred[q];
      var_s = tt / 361.f;
    }
    __syncthreads();
    const float xn = gam * (y - mu) * (1.0f / sqrtf(var_s + 1e-5f)) + bet;

    float v;
    if (stage == 0) {
      v = fmaxf(p[0] * xn, 0.f);
      d2 = v;
    } else if (stage == 7) {
      v = fmaxf(xn, 0.f);
    } else if (stage & 1) {
      v = fmaxf(p[stage] * xn, 0.f);
    } else {
      v = fmaxf(p[stage] * xn + d2, 0.f);
      d2 = v;
    }
    if (act) nxt[tid] = v;
    __syncthreads();
    float* tmp = cur; cur = nxt; nxt = tmp;
  }
  if (act) d1g[tid] = cur[tid];
}

// ---------------------------------------------------------------------------
// K2: feat = W_lin @ d1 + b_lin.
// ---------------------------------------------------------------------------
__global__ __launch_bounds__(256) void k_feat(
    const float* __restrict__ W_lin, const float* __restrict__ b_lin,
    const float* __restrict__ d1g, float* __restrict__ feat) {
  const int wid = threadIdx.x >> 6, lane = threadIdx.x & 63;
  const int rbase = blockIdx.x * 16 + wid * 4;
  for (int rr = 0; rr < 4; rr++) {
    const int r = rbase + rr;
    const float* wrow = W_lin + r * 361;
    float s = 0.f;
    for (int k = lane; k < 361; k += 64) s += wrow[k] * d1g[k];
#pragma unroll
    for (int o = 32; o > 0; o >>= 1) s += __shfl_xor(s, o);
    if (lane == 0) feat[r] = s + b_lin[r];
  }
}

// ---------------------------------------------------------------------------
// K3: LSTM chain. 4 WGs x 512 threads (PROVEN round-0 comm protocol:
// agent-scope relaxed tagged packets, double-buffered by step parity).
// NEW matvec: wave w is uniform in column-half (half = w&1, gate = w>>1,
// row = gate*64+lane). Each thread pulls its h-half into 2 lane regs
// (2 ds_read_b32), then dots 128 columns via v_readlane SGPR broadcast +
// v_fmac — no LDS-unit traffic in the inner loop (was 32 ds_read_b128/thr).
// 4 partial accumulators break the fma dependence chain.
// ---------------------------------------------------------------------------
__global__ __launch_bounds__(512) void k_lstm(
    const float* __restrict__ W_ih, const float* __restrict__ b_ih,
    const float* __restrict__ W_hh, const float* __restrict__ b_hh,
    const float* __restrict__ feat, float* __restrict__ h_all,
    unsigned long long* hcomm) {
  __shared__ float h_lds[EMB];
  __shared__ float gbuf[2][EMB];   // [half][gate*64 + j]
  const int g = blockIdx.x;
  const int tid = threadIdx.x;
  const int w = tid >> 6, lane = tid & 63;
  const int half = w & 1;          // which 128-column half this wave dots
  const int gate = w >> 1;         // 0..3 (i,f,g,o)
  const int rloc = gate * 64 + lane;
  const int R = gate * 256 + g * 64 + lane;   // global gate row
  const float bsum = b_ih[R] + b_hh[R];

  float4 w4[32];   // 128 weight columns [half*128, half*128+128)
  {
    const float4* wih = (const float4*)(W_ih + R * EMB + half * 128);
#pragma unroll
    for (int q = 0; q < 32; q++) w4[q] = wih[q];
  }
  if (tid < EMB) h_lds[tid] = feat[tid];  // x_in for step 0
  float c = 0.f;
  __syncthreads();

  for (int t = 0; t <= 100; t++) {
    // pull this wave's h-half into lane regs: lane l holds h[half*128+l], h[half*128+64+l]
    const float hv0 = h_lds[half * 128 + lane];
    const float hv1 = h_lds[half * 128 + 64 + lane];

    // 128-column dot via readlane broadcast (4 independent partial chains)
    float a0 = (half == 0) ? bsum : 0.f, a1 = 0.f, a2 = 0.f, a3 = 0.f;
#pragma unroll
    for (int k = 0; k < 32; k++) {
      const float4 wv = w4[k];
      const float h0 = __uint_as_float(__builtin_amdgcn_readlane(
          __float_as_uint(k < 16 ? hv0 : hv0), (4 * k) & 63));
      // note: columns 0..63 come from hv0, 64..127 from hv1
      const int kk = 4 * k;
      const float s0 = __uint_as_float(__builtin_amdgcn_readlane(
          __float_as_uint(kk + 0 < 64 ? hv0 : hv1), (kk + 0) & 63));
      const float s1 = __uint_as_float(__builtin_amdgcn_readlane(
          __float_as_uint(kk + 1 < 64 ? hv0 : hv1), (kk + 1) & 63));
      const float s2 = __uint_as_float(__builtin_amdgcn_readlane(
          __float_as_uint(kk + 2 < 64 ? hv0 : hv1), (kk + 2) & 63));
      const float s3 = __uint_as_float(__builtin_amdgcn_readlane(
          __float_as_uint(kk + 3 < 64 ? hv0 : hv1), (kk + 3) & 63));
      (void)h0;
      a0 = fmaf(s0, wv.x, a0);
      a1 = fmaf(s1, wv.y, a1);
      a2 = fmaf(s2, wv.z, a2);
      a3 = fmaf(s3, wv.w, a3);
    }
    gbuf[half][rloc] = (a0 + a1) + (a2 + a3);
    __syncthreads();  // B1: gbuf ready; h_lds reads of this step done

    if (tid < 64) {
      const float gi = gbuf[0][tid]       + gbuf[1][tid];
      const float gf = gbuf[0][64 + tid]  + gbuf[1][64 + tid];
      const float gg = gbuf[0][128 + tid] + gbuf[1][128 + tid];
      const float go = gbuf[0][192 + tid] + gbuf[1][192 + tid];
      c = sigf(gf) * c + sigf(gi) * tanhf(gg);
      const float h = sigf(go) * tanhf(c);
      const int j = g * 64 + tid;
      h_all[t * EMB + j] = h;   // for k_dec (kernel-boundary visibility)
      h_lds[j] = h;             // local fast path: no self-poll needed
      if (t < 100) {
        unsigned long long pkt =
            ((unsigned long long)(unsigned)(t + 1) << 32) | (unsigned long long)__float_as_uint(h);
        __hip_atomic_store(&hcomm[(t & 1) * EMB + j], pkt,
                           __ATOMIC_RELAXED, __HIP_MEMORY_SCOPE_AGENT);
      }
    }
    if (t < 100) {
      if (tid < EMB && (tid < g * 64 || tid >= g * 64 + 64)) {  // remote slots only
        const unsigned long long* slot = &hcomm[(t & 1) * EMB + tid];
        unsigned long long u;
        while (1) {
          u = __hip_atomic_load(slot, __ATOMIC_RELAXED, __HIP_MEMORY_SCOPE_AGENT);
          if ((unsigned)(u >> 32) == (unsigned)(t + 1)) break;
          __builtin_amdgcn_s_sleep(1);
        }
        h_lds[tid] = __uint_as_float((unsigned)u);
      }
      __syncthreads();  // B2: h_lds(t+1) ready for everyone
    }
    if (t == 0) {  // switch to W_sum = W_ih + W_hh for steps >= 1
      const float4* whh = (const float4*)(W_hh + R * EMB + half * 128);
#pragma unroll
      for (int q = 0; q < 32; q++) {
        float4 a = whh[q];
        w4[q].x += a.x; w4[q].y += a.y; w4[q].z += a.z; w4[q].w += a.w;
      }
    }
  }
}

// ---------------------------------------------------------------------------
// K4: decode GEMM  out[t][v] = relu(W_dec[v,:] . h_all[t,:] + b_dec[v])
// 196 blocks x 512 thr. Per block: Vtile=256 (4 rows/thread -> each broadcast
// LDS h-read feeds 4 output rows: halves LDS instruction count vs 2 rows),
// tg = tid>>6 covers 13 t-rows. W streamed global->regs in 4-float4 chunks.
// ---------------------------------------------------------------------------
__global__ __launch_bounds__(512) void k_dec(
    const float* __restrict__ W_dec, const float* __restrict__ b_dec,
    const float* __restrict__ h_all, float* __restrict__ out) {
  __shared__ float4 ldsH[104 * 32];  // 104 t-rows x 32 float4 (K-chunk 128)
  const int tid = threadIdx.x;
  const int vp = tid & 63, tg = tid >> 6;   // tg 0..7 -> 13 t-rows each
  const int vb = blockIdx.x * 256 + vp;
  int r[4];
#pragma unroll
  for (int m = 0; m < 4; m++) {
    const int v = vb + m * 64;
    r[m] = v < VOCAB ? v : VOCAB - 1;
  }
  const float4* h4g = (const float4*)h_all;

  float acc[4][13];
#pragma unroll
  for (int m = 0; m < 4; m++)
#pragma unroll
    for (int q = 0; q < 13; q++) acc[m][q] = 0.f;

  for (int ch = 0; ch < 2; ch++) {
    if (ch) __syncthreads();  // protect LDS reuse
    for (int f = tid; f < 104 * 32; f += 512) {
      const int t = f >> 5, cc = f & 31;
      float4 val = make_float4(0.f, 0.f, 0.f, 0.f);
      if (t < TROWS) val = h4g[t * 64 + ch * 32 + cc];
      ldsH[t * 32 + cc] = val;
    }
    __syncthreads();

    for (int k4 = 0; k4 < 8; k4++) {
      float4 wreg[4][4];
#pragma unroll
      for (int m = 0; m < 4; m++) {
        const float4* wr = (const float4*)(W_dec + r[m] * EMB) + ch * 32 + k4 * 4;
#pragma unroll
        for (int jj = 0; jj < 4; jj++) wreg[m][jj] = wr[jj];
      }
#pragma unroll
      for (int q = 0; q < 13; q++) {
        const float4* hrow = &ldsH[(tg * 13 + q) * 32 + k4 * 4];
#pragma unroll
        for (int jj = 0; jj < 4; jj++) {
          const float4 h = hrow[jj];
#pragma unroll
          for (int m = 0; m < 4; m++) {
            acc[m][q] += wreg[m][jj].x * h.x + wreg[m][jj].y * h.y +
                         wreg[m][jj].z * h.z + wreg[m][jj].w * h.w;
          }
        }
      }
    }
  }
#pragma unroll
  for (int m = 0; m < 4; m++) {
    const float bd = b_dec[r[m]];
    const int v = vb + m * 64;
#pragma unroll
    for (int q = 0; q < 13; q++) {
      const int t = tg * 13 + q;
      if (t < TROWS && v < VOCAB) out[t * VOCAB + v] = fmaxf(acc[m][q] + bd, 0.f);
    }
  }
}

// ---------------------------------------------------------------------------
extern "C" void kernel_launch(void* const* d_in, const int* in_sizes, int n_in,
                              void* d_out, int out_size, void* d_ws, size_t ws_size,
                              hipStream_t stream) {
  const float* board  = (const float*)d_in[0];
  const float* conv_w = (const float*)d_in[1];
  const float* conv_b = (const float*)d_in[2];
  const float* bn_g   = (const float*)d_in[3];
  const float* bn_b   = (const float*)d_in[4];
  const float* p      = (const float*)d_in[5];
  const float* W_lin  = (const float*)d_in[6];
  const float* b_lin  = (const float*)d_in[7];
  const float* W_ih   = (const float*)d_in[8];
  const float* b_ih   = (const float*)d_in[9];
  const float* W_hh   = (const float*)d_in[10];
  const float* b_hh   = (const float*)d_in[11];
  const float* W_dec  = (const float*)d_in[12];
  const float* b_dec  = (const float*)d_in[13];

  float* wsf   = (float*)d_ws;
  float* feat  = wsf;                        // 256 floats
  float* d1g   = wsf + 256;                  // 384 slot (361 used)
  float* h_all = wsf + 640;                  // 101*256 floats
  unsigned long long* hcomm =
      (unsigned long long*)(wsf + 640 + 104 * 256);  // 512 u64 (8B aligned)
  // hcomm needs no init: poison 0xAAAAAAAA never matches a valid tag in [1,100].

  k_conv<<<1, 384, 0, stream>>>(board, conv_w, conv_b, bn_g, bn_b, p, d1g);
  k_feat<<<16, 256, 0, stream>>>(W_lin, b_lin, d1g, feat);
  k_lstm<<<NWG, 512, 0, stream>>>(W_ih, b_ih, W_hh, b_hh, feat, h_all, hcomm);
  k_dec<<<(VOCAB + 255) / 256, 512, 0, stream>>>(W_dec, b_dec, h_all, (float*)d_out);
}

// Round 3
// 565.188 us; speedup vs baseline: 6.7913x; 1.6558x over previous
//
#include <hip/hip_runtime.h>
#include <math.h>

#define EMB 256
#define VOCAB 50000
#define TROWS 101
#define NWG 4           // LSTM workgroups (4 x 512 threads) — proven layout

__device__ __forceinline__ float sigf(float x) { return 1.0f / (1.0f + expf(-x)); }

// ---------------------------------------------------------------------------
// K1: conv tower (8 shared-weight conv3x3 + batchnorm stages), single block.
// ---------------------------------------------------------------------------
__global__ __launch_bounds__(384) void k_conv(
    const float* __restrict__ board, const float* __restrict__ conv_w,
    const float* __restrict__ conv_b, const float* __restrict__ bn_g,
    const float* __restrict__ bn_b, const float* __restrict__ p,
    float* __restrict__ d1g) {
  __shared__ float xa[361], xb[361];
  __shared__ float wred[6];
  __shared__ float mu_s, var_s;
  const int tid = threadIdx.x;
  const bool act = tid < 361;
  const int i = tid / 19, j = tid % 19;
  float cw[9];
#pragma unroll
  for (int q = 0; q < 9; q++) cw[q] = conv_w[q];
  const float cb = conv_b[0], gam = bn_g[0], bet = bn_b[0];
  if (act) xa[tid] = board[tid];
  __syncthreads();

  float d2 = 0.f;
  float* cur = xa;
  float* nxt = xb;
  for (int stage = 0; stage < 8; stage++) {
    float y = 0.f;
    if (act) {
#pragma unroll
      for (int di = 0; di < 3; di++) {
#pragma unroll
        for (int dj = 0; dj < 3; dj++) {
          int ii = i + di - 1, jj = j + dj - 1;
          float xv = (ii >= 0 && ii < 19 && jj >= 0 && jj < 19) ? cur[ii * 19 + jj] : 0.f;
          y += cw[di * 3 + dj] * xv;
        }
      }
      y += cb;
    }
    float s = act ? y : 0.f;
#pragma unroll
    for (int o = 32; o > 0; o >>= 1) s += __shfl_xor(s, o);
    if ((tid & 63) == 0) wred[tid >> 6] = s;
    __syncthreads();
    if (tid == 0) {
      float tt = 0.f;
      for (int q = 0; q < 6; q++) tt += wred[q];
      mu_s = tt / 361.f;
    }
    __syncthreads();
    const float mu = mu_s;
    float d = act ? (y - mu) : 0.f;
    s = d * d;
#pragma unroll
    for (int o = 32; o > 0; o >>= 1) s += __shfl_xor(s, o);
    if ((tid & 63) == 0) wred[tid >> 6] = s;
    __syncthreads();
    if (tid == 0) {
      float tt = 0.f;
      for (int q = 0; q < 6; q++) tt += wred[q];
      var_s = tt / 361.f;
    }
    __syncthreads();
    const float xn = gam * (y - mu) * (1.0f / sqrtf(var_s + 1e-5f)) + bet;

    float v;
    if (stage == 0) {
      v = fmaxf(p[0] * xn, 0.f);
      d2 = v;
    } else if (stage == 7) {
      v = fmaxf(xn, 0.f);
    } else if (stage & 1) {
      v = fmaxf(p[stage] * xn, 0.f);
    } else {
      v = fmaxf(p[stage] * xn + d2, 0.f);
      d2 = v;
    }
    if (act) nxt[tid] = v;
    __syncthreads();
    float* tmp = cur; cur = nxt; nxt = tmp;
  }
  if (act) d1g[tid] = cur[tid];
}

// ---------------------------------------------------------------------------
// K2: feat = W_lin @ d1 + b_lin.
// ---------------------------------------------------------------------------
__global__ __launch_bounds__(256) void k_feat(
    const float* __restrict__ W_lin, const float* __restrict__ b_lin,
    const float* __restrict__ d1g, float* __restrict__ feat) {
  const int wid = threadIdx.x >> 6, lane = threadIdx.x & 63;
  const int rbase = blockIdx.x * 16 + wid * 4;
  for (int rr = 0; rr < 4; rr++) {
    const int r = rbase + rr;
    const float* wrow = W_lin + r * 361;
    float s = 0.f;
    for (int k = lane; k < 361; k += 64) s += wrow[k] * d1g[k];
#pragma unroll
    for (int o = 32; o > 0; o >>= 1) s += __shfl_xor(s, o);
    if (lane == 0) feat[r] = s + b_lin[r];
  }
}

// ---------------------------------------------------------------------------
// K3: LSTM chain — UNCHANGED round-2 structure (passed, absmax 4.9e-4),
// except: additionally writes transposed h_allT[j][t] (pad-104 rows) for
// k_dec's lane-parallel h access. One extra fire-and-forget store per step.
// ---------------------------------------------------------------------------
__global__ __launch_bounds__(512) void k_lstm(
    const float* __restrict__ W_ih, const float* __restrict__ b_ih,
    const float* __restrict__ W_hh, const float* __restrict__ b_hh,
    const float* __restrict__ feat, float* __restrict__ h_all,
    float* __restrict__ h_allT, unsigned long long* hcomm) {
  __shared__ float h_lds[EMB];
  __shared__ float gbuf[2][EMB];   // [half][gate*64 + j]
  const int g = blockIdx.x;
  const int tid = threadIdx.x;
  const int w = tid >> 6, lane = tid & 63;
  const int half = w & 1;          // which 128-column half this wave dots
  const int gate = w >> 1;         // 0..3 (i,f,g,o)
  const int rloc = gate * 64 + lane;
  const int R = gate * 256 + g * 64 + lane;   // global gate row
  const float bsum = b_ih[R] + b_hh[R];

  float4 w4[32];   // 128 weight columns [half*128, half*128+128)
  {
    const float4* wih = (const float4*)(W_ih + R * EMB + half * 128);
#pragma unroll
    for (int q = 0; q < 32; q++) w4[q] = wih[q];
  }
  if (tid < EMB) h_lds[tid] = feat[tid];  // x_in for step 0
  float c = 0.f;
  __syncthreads();

  for (int t = 0; t <= 100; t++) {
    // pull this wave's h-half into lane regs
    const float hv0 = h_lds[half * 128 + lane];
    const float hv1 = h_lds[half * 128 + 64 + lane];

    // 128-column dot via readlane broadcast (4 independent partial chains)
    float a0 = (half == 0) ? bsum : 0.f, a1 = 0.f, a2 = 0.f, a3 = 0.f;
#pragma unroll
    for (int k = 0; k < 32; k++) {
      const float4 wv = w4[k];
      const int kk = 4 * k;
      const float s0 = __uint_as_float(__builtin_amdgcn_readlane(
          __float_as_uint(kk + 0 < 64 ? hv0 : hv1), (kk + 0) & 63));
      const float s1 = __uint_as_float(__builtin_amdgcn_readlane(
          __float_as_uint(kk + 1 < 64 ? hv0 : hv1), (kk + 1) & 63));
      const float s2 = __uint_as_float(__builtin_amdgcn_readlane(
          __float_as_uint(kk + 2 < 64 ? hv0 : hv1), (kk + 2) & 63));
      const float s3 = __uint_as_float(__builtin_amdgcn_readlane(
          __float_as_uint(kk + 3 < 64 ? hv0 : hv1), (kk + 3) & 63));
      a0 = fmaf(s0, wv.x, a0);
      a1 = fmaf(s1, wv.y, a1);
      a2 = fmaf(s2, wv.z, a2);
      a3 = fmaf(s3, wv.w, a3);
    }
    gbuf[half][rloc] = (a0 + a1) + (a2 + a3);
    __syncthreads();  // B1: gbuf ready; h_lds reads of this step done

    if (tid < 64) {
      const float gi = gbuf[0][tid]       + gbuf[1][tid];
      const float gf = gbuf[0][64 + tid]  + gbuf[1][64 + tid];
      const float gg = gbuf[0][128 + tid] + gbuf[1][128 + tid];
      const float go = gbuf[0][192 + tid] + gbuf[1][192 + tid];
      c = sigf(gf) * c + sigf(gi) * tanhf(gg);
      const float h = sigf(go) * tanhf(c);
      const int j = g * 64 + tid;
      h_all[t * EMB + j] = h;     // kernel-boundary visibility
      h_allT[j * 104 + t] = h;    // transposed copy for k_dec
      h_lds[j] = h;               // local fast path: no self-poll needed
      if (t < 100) {
        unsigned long long pkt =
            ((unsigned long long)(unsigned)(t + 1) << 32) | (unsigned long long)__float_as_uint(h);
        __hip_atomic_store(&hcomm[(t & 1) * EMB + j], pkt,
                           __ATOMIC_RELAXED, __HIP_MEMORY_SCOPE_AGENT);
      }
    }
    if (t < 100) {
      if (tid < EMB && (tid < g * 64 || tid >= g * 64 + 64)) {  // remote slots only
        const unsigned long long* slot = &hcomm[(t & 1) * EMB + tid];
        unsigned long long u;
        while (1) {
          u = __hip_atomic_load(slot, __ATOMIC_RELAXED, __HIP_MEMORY_SCOPE_AGENT);
          if ((unsigned)(u >> 32) == (unsigned)(t + 1)) break;
          __builtin_amdgcn_s_sleep(1);
        }
        h_lds[tid] = __uint_as_float((unsigned)u);
      }
      __syncthreads();  // B2: h_lds(t+1) ready for everyone
    }
    if (t == 0) {  // switch to W_sum = W_ih + W_hh for steps >= 1
      const float4* whh = (const float4*)(W_hh + R * EMB + half * 128);
#pragma unroll
      for (int q = 0; q < 32; q++) {
        float4 a = whh[q];
        w4[q].x += a.x; w4[q].y += a.y; w4[q].z += a.z; w4[q].w += a.w;
      }
    }
  }
}

// ---------------------------------------------------------------------------
// K4: decode GEMM  out[t][v] = relu(W_dec[v,:] . h_all[t,:] + b_dec[v])
// REDESIGNED for coalesced W access (round-2 had 13.6x HBM over-fetch from
// 1KB-strided lane gathers):
//   - 196 blocks x 256 thr; block owns 256 vocab rows, thread owns ONE row v
//     with acc[101] in VGPRs (no cross-lane reduce).
//   - W staged global->LDS in k-chunks of 32: fully-coalesced float4 reads
//     (each 128B segment consumed entirely), stored TRANSPOSED [k][v] with
//     XOR swizzle (v ^ ((k&15)<<2)): compute reads conflict-free, writes 4-way.
//   - h[t][k] broadcast: two lane-regs hold h_allT[k][0..103]; per (k,t) a
//     v_readlane feeds the SGPR operand of v_fmac. No LDS h traffic.
// ---------------------------------------------------------------------------
__global__ __launch_bounds__(256, 1) void k_dec(
    const float* __restrict__ W_dec, const float* __restrict__ b_dec,
    const float* __restrict__ h_allT, float* __restrict__ out) {
  __shared__ float lds_w[32 * 256];  // [k][v] swizzled, 32 KB
  const int tid = threadIdx.x;
  const int lane = tid & 63;
  const int vb = blockIdx.x * 256;
  const int v = vb + tid;

  float acc[TROWS];
#pragma unroll
  for (int t = 0; t < TROWS; t++) acc[t] = 0.f;

  for (int kc = 0; kc < 8; kc++) {
    __syncthreads();  // protect LDS reuse
    // ---- stage W chunk [256 rows x 32 k], coalesced, transposed+swizzled ----
#pragma unroll
    for (int i = 0; i < 8; i++) {
      const int f = tid + i * 256;      // 0..2047
      const int row = f >> 3;           // 0..255
      const int cc = f & 7;             // float4 index within 32-k chunk
      int rg = vb + row;
      rg = rg < VOCAB ? rg : VOCAB - 1;
      const float4 wv = *(const float4*)(W_dec + rg * EMB + kc * 32 + cc * 4);
      const int k0 = cc * 4;
      lds_w[(k0 + 0) * 256 + (row ^ (((k0 + 0) & 15) << 2))] = wv.x;
      lds_w[(k0 + 1) * 256 + (row ^ (((k0 + 1) & 15) << 2))] = wv.y;
      lds_w[(k0 + 2) * 256 + (row ^ (((k0 + 2) & 15) << 2))] = wv.z;
      lds_w[(k0 + 3) * 256 + (row ^ (((k0 + 3) & 15) << 2))] = wv.w;
    }
    __syncthreads();

    // ---- compute: 32 k-steps, 101 fma each ----
#pragma unroll 1
    for (int k = 0; k < 32; k++) {
      const int kg = kc * 32 + k;
      const float vh0 = h_allT[kg * 104 + lane];        // h[kg][t=lane]
      const float vh1 = h_allT[kg * 104 + 64 + lane];   // h[kg][t=64+lane] (pad garbage unused)
      const float w = lds_w[k * 256 + (tid ^ ((k & 15) << 2))];
#pragma unroll
      for (int t = 0; t < TROWS; t++) {
        const float s = __uint_as_float(__builtin_amdgcn_readlane(
            __float_as_uint(t < 64 ? vh0 : vh1), t & 63));
        acc[t] = fmaf(s, w, acc[t]);
      }
    }
  }

  const int rc = v < VOCAB ? v : VOCAB - 1;
  const float bd = b_dec[rc];
  if (v < VOCAB) {
#pragma unroll 1
    for (int t = 0; t < TROWS; t++) {
      out[t * VOCAB + v] = fmaxf(acc[t] + bd, 0.f);
    }
  }
}

// ---------------------------------------------------------------------------
extern "C" void kernel_launch(void* const* d_in, const int* in_sizes, int n_in,
                              void* d_out, int out_size, void* d_ws, size_t ws_size,
                              hipStream_t stream) {
  const float* board  = (const float*)d_in[0];
  const float* conv_w = (const float*)d_in[1];
  const float* conv_b = (const float*)d_in[2];
  const float* bn_g   = (const float*)d_in[3];
  const float* bn_b   = (const float*)d_in[4];
  const float* p      = (const float*)d_in[5];
  const float* W_lin  = (const float*)d_in[6];
  const float* b_lin  = (const float*)d_in[7];
  const float* W_ih   = (const float*)d_in[8];
  const float* b_ih   = (const float*)d_in[9];
  const float* W_hh   = (const float*)d_in[10];
  const float* b_hh   = (const float*)d_in[11];
  const float* W_dec  = (const float*)d_in[12];
  const float* b_dec  = (const float*)d_in[13];

  float* wsf   = (float*)d_ws;
  float* feat  = wsf;                        // 256 floats
  float* d1g   = wsf + 256;                  // 384 slot (361 used)
  float* h_all = wsf + 640;                  // 104*256 floats
  unsigned long long* hcomm =
      (unsigned long long*)(wsf + 640 + 104 * 256);   // 512 u64 (8B aligned)
  float* h_allT = wsf + 640 + 104 * 256 + 1024;       // 256*104 floats
  // hcomm needs no init: poison 0xAAAAAAAA never matches a valid tag in [1,100].
  // h_allT pad (t=101..103) is garbage but never consumed (readlane t<=100).

  k_conv<<<1, 384, 0, stream>>>(board, conv_w, conv_b, bn_g, bn_b, p, d1g);
  k_feat<<<16, 256, 0, stream>>>(W_lin, b_lin, d1g, feat);
  k_lstm<<<NWG, 512, 0, stream>>>(W_ih, b_ih, W_hh, b_hh, feat, h_all, h_allT, hcomm);
  k_dec<<<(VOCAB + 255) / 256, 256, 0, stream>>>(W_dec, b_dec, h_allT, (float*)d_out);
}

// Round 4
// 510.573 us; speedup vs baseline: 7.5177x; 1.1070x over previous
//
#include <hip/hip_runtime.h>
#include <math.h>

#define EMB 256
#define VOCAB 50000
#define TROWS 101
#define NLB 32   // lstm launch blocks; 4 same-XCD workers elected at runtime
#define NW 4     // lstm worker workgroups

__device__ __forceinline__ float sigf(float x) { return 1.0f / (1.0f + expf(-x)); }

// ---------------------------------------------------------------------------
// K1: conv tower (8 shared-weight conv3x3 + batchnorm stages), single block.
// ---------------------------------------------------------------------------
__global__ __launch_bounds__(384) void k_conv(
    const float* __restrict__ board, const float* __restrict__ conv_w,
    const float* __restrict__ conv_b, const float* __restrict__ bn_g,
    const float* __restrict__ bn_b, const float* __restrict__ p,
    float* __restrict__ d1g) {
  __shared__ float xa[361], xb[361];
  __shared__ float wred[6];
  __shared__ float mu_s, var_s;
  const int tid = threadIdx.x;
  const bool act = tid < 361;
  const int i = tid / 19, j = tid % 19;
  float cw[9];
#pragma unroll
  for (int q = 0; q < 9; q++) cw[q] = conv_w[q];
  const float cb = conv_b[0], gam = bn_g[0], bet = bn_b[0];
  if (act) xa[tid] = board[tid];
  __syncthreads();

  float d2 = 0.f;
  float* cur = xa;
  float* nxt = xb;
  for (int stage = 0; stage < 8; stage++) {
    float y = 0.f;
    if (act) {
#pragma unroll
      for (int di = 0; di < 3; di++) {
#pragma unroll
        for (int dj = 0; dj < 3; dj++) {
          int ii = i + di - 1, jj = j + dj - 1;
          float xv = (ii >= 0 && ii < 19 && jj >= 0 && jj < 19) ? cur[ii * 19 + jj] : 0.f;
          y += cw[di * 3 + dj] * xv;
        }
      }
      y += cb;
    }
    float s = act ? y : 0.f;
#pragma unroll
    for (int o = 32; o > 0; o >>= 1) s += __shfl_xor(s, o);
    if ((tid & 63) == 0) wred[tid >> 6] = s;
    __syncthreads();
    if (tid == 0) {
      float tt = 0.f;
      for (int q = 0; q < 6; q++) tt += wred[q];
      mu_s = tt / 361.f;
    }
    __syncthreads();
    const float mu = mu_s;
    float d = act ? (y - mu) : 0.f;
    s = d * d;
#pragma unroll
    for (int o = 32; o > 0; o >>= 1) s += __shfl_xor(s, o);
    if ((tid & 63) == 0) wred[tid >> 6] = s;
    __syncthreads();
    if (tid == 0) {
      float tt = 0.f;
      for (int q = 0; q < 6; q++) tt += wred[q];
      var_s = tt / 361.f;
    }
    __syncthreads();
    const float xn = gam * (y - mu) * (1.0f / sqrtf(var_s + 1e-5f)) + bet;

    float v;
    if (stage == 0) {
      v = fmaxf(p[0] * xn, 0.f);
      d2 = v;
    } else if (stage == 7) {
      v = fmaxf(xn, 0.f);
    } else if (stage & 1) {
      v = fmaxf(p[stage] * xn, 0.f);
    } else {
      v = fmaxf(p[stage] * xn + d2, 0.f);
      d2 = v;
    }
    if (act) nxt[tid] = v;
    __syncthreads();
    float* tmp = cur; cur = nxt; nxt = tmp;
  }
  if (act) d1g[tid] = cur[tid];
}

// ---------------------------------------------------------------------------
// K2: feat = W_lin @ d1 + b_lin.
// ---------------------------------------------------------------------------
__global__ __launch_bounds__(256) void k_feat(
    const float* __restrict__ W_lin, const float* __restrict__ b_lin,
    const float* __restrict__ d1g, float* __restrict__ feat) {
  const int wid = threadIdx.x >> 6, lane = threadIdx.x & 63;
  const int rbase = blockIdx.x * 16 + wid * 4;
  for (int rr = 0; rr < 4; rr++) {
    const int r = rbase + rr;
    const float* wrow = W_lin + r * 361;
    float s = 0.f;
    for (int k = lane; k < 361; k += 64) s += wrow[k] * d1g[k];
#pragma unroll
    for (int o = 32; o > 0; o >>= 1) s += __shfl_xor(s, o);
    if (lane == 0) feat[r] = s + b_lin[r];
  }
}

// ---------------------------------------------------------------------------
// K3: LSTM chain. 32 blocks launched; 4 workers elected on ONE measured XCD
// (pigeonhole over 8 XCDs; election machinery proven in round 1). Comm is the
// PROVEN round-0 protocol, byte-identical: agent-scope relaxed tagged u64
// packets, double-buffered by step parity. Only deltas vs round 3:
//   - same-XCD placement (tests whether agent ops resolve below MALL)
//   - poll spin has no s_sleep (cuts retry quantization)
// Matvec: readlane-broadcast VALU dot (proven round 2/3).
// ---------------------------------------------------------------------------
__global__ __launch_bounds__(512) void k_lstm(
    const float* __restrict__ W_ih, const float* __restrict__ b_ih,
    const float* __restrict__ W_hh, const float* __restrict__ b_hh,
    const float* __restrict__ feat, float* __restrict__ h_all,
    float* __restrict__ h_allT, unsigned long long* hcomm,
    unsigned long long* xtab) {
  __shared__ float h_lds[EMB];
  __shared__ float gbuf[2][EMB];   // [half][gate*64 + j]
  __shared__ int sxcd[NLB];
  const int tid = threadIdx.x;

  // ---- same-XCD election (once; all blocks resident => no deadlock) ----
  if (tid == 0) {
    // s_getreg hwreg(HW_REG_XCC_ID=20, offset 0, size 32) -> simm 63508
    unsigned xcc = __builtin_amdgcn_s_getreg(63508) & 7u;
    __hip_atomic_store(&xtab[blockIdx.x],
                       0xE1EC000000000000ULL | (unsigned long long)xcc,
                       __ATOMIC_RELAXED, __HIP_MEMORY_SCOPE_AGENT);
  }
  if (tid < NLB) {
    const unsigned long long* slot = &xtab[tid];
    unsigned long long u;
    while (1) {
      u = __hip_atomic_load(slot, __ATOMIC_RELAXED, __HIP_MEMORY_SCOPE_AGENT);
      if ((unsigned)(u >> 32) == 0xE1EC0000u) break;
      __builtin_amdgcn_s_sleep(2);
    }
    sxcd[tid] = (int)((unsigned)u & 7u);
  }
  __syncthreads();
  int target = -1;
  for (int x = 0; x < 8; x++) {
    int n = 0;
    for (int b = 0; b < NLB; b++) n += (sxcd[b] == x);
    if (n >= NW) { target = x; break; }
  }
  int rank = -1, seen = 0;
  for (int b = 0; b < NLB; b++) {
    if (sxcd[b] == target) {
      if (b == (int)blockIdx.x) rank = seen;
      seen++;
    }
  }
  if (rank < 0 || rank >= NW) return;  // non-worker block exits
  const int g = rank;                  // worker slice index (same XCD for all)

  // ---- LSTM body (identical math to round 3) ----
  const int w = tid >> 6, lane = tid & 63;
  const int half = w & 1;          // which 128-column half this wave dots
  const int gate = w >> 1;         // 0..3 (i,f,g,o)
  const int rloc = gate * 64 + lane;
  const int R = gate * 256 + g * 64 + lane;   // global gate row
  const float bsum = b_ih[R] + b_hh[R];

  float4 w4[32];   // 128 weight columns [half*128, half*128+128)
  {
    const float4* wih = (const float4*)(W_ih + R * EMB + half * 128);
#pragma unroll
    for (int q = 0; q < 32; q++) w4[q] = wih[q];
  }
  if (tid < EMB) h_lds[tid] = feat[tid];  // x_in for step 0
  float c = 0.f;
  __syncthreads();

  for (int t = 0; t <= 100; t++) {
    // pull this wave's h-half into lane regs
    const float hv0 = h_lds[half * 128 + lane];
    const float hv1 = h_lds[half * 128 + 64 + lane];

    // 128-column dot via readlane broadcast (4 independent partial chains)
    float a0 = (half == 0) ? bsum : 0.f, a1 = 0.f, a2 = 0.f, a3 = 0.f;
#pragma unroll
    for (int k = 0; k < 32; k++) {
      const float4 wv = w4[k];
      const int kk = 4 * k;
      const float s0 = __uint_as_float(__builtin_amdgcn_readlane(
          __float_as_uint(kk + 0 < 64 ? hv0 : hv1), (kk + 0) & 63));
      const float s1 = __uint_as_float(__builtin_amdgcn_readlane(
          __float_as_uint(kk + 1 < 64 ? hv0 : hv1), (kk + 1) & 63));
      const float s2 = __uint_as_float(__builtin_amdgcn_readlane(
          __float_as_uint(kk + 2 < 64 ? hv0 : hv1), (kk + 2) & 63));
      const float s3 = __uint_as_float(__builtin_amdgcn_readlane(
          __float_as_uint(kk + 3 < 64 ? hv0 : hv1), (kk + 3) & 63));
      a0 = fmaf(s0, wv.x, a0);
      a1 = fmaf(s1, wv.y, a1);
      a2 = fmaf(s2, wv.z, a2);
      a3 = fmaf(s3, wv.w, a3);
    }
    gbuf[half][rloc] = (a0 + a1) + (a2 + a3);
    __syncthreads();  // B1: gbuf ready; h_lds reads of this step done

    if (tid < 64) {
      const float gi = gbuf[0][tid]       + gbuf[1][tid];
      const float gf = gbuf[0][64 + tid]  + gbuf[1][64 + tid];
      const float gg = gbuf[0][128 + tid] + gbuf[1][128 + tid];
      const float go = gbuf[0][192 + tid] + gbuf[1][192 + tid];
      c = sigf(gf) * c + sigf(gi) * tanhf(gg);
      const float h = sigf(go) * tanhf(c);
      const int j = g * 64 + tid;
      h_all[t * EMB + j] = h;     // kernel-boundary visibility
      h_allT[j * 104 + t] = h;    // transposed copy for k_dec
      h_lds[j] = h;               // local fast path: no self-poll needed
      if (t < 100) {
        unsigned long long pkt =
            ((unsigned long long)(unsigned)(t + 1) << 32) | (unsigned long long)__float_as_uint(h);
        __hip_atomic_store(&hcomm[(t & 1) * EMB + j], pkt,
                           __ATOMIC_RELAXED, __HIP_MEMORY_SCOPE_AGENT);
      }
    }
    if (t < 100) {
      if (tid < EMB && (tid < g * 64 || tid >= g * 64 + 64)) {  // remote slots only
        const unsigned long long* slot = &hcomm[(t & 1) * EMB + tid];
        unsigned long long u;
        while (1) {
          u = __hip_atomic_load(slot, __ATOMIC_RELAXED, __HIP_MEMORY_SCOPE_AGENT);
          if ((unsigned)(u >> 32) == (unsigned)(t + 1)) break;
          // tight spin (no s_sleep): shave retry quantization off critical path
        }
        h_lds[tid] = __uint_as_float((unsigned)u);
      }
      __syncthreads();  // B2: h_lds(t+1) ready for everyone
    }
    if (t == 0) {  // switch to W_sum = W_ih + W_hh for steps >= 1
      const float4* whh = (const float4*)(W_hh + R * EMB + half * 128);
#pragma unroll
      for (int q = 0; q < 32; q++) {
        float4 a = whh[q];
        w4[q].x += a.x; w4[q].y += a.y; w4[q].z += a.z; w4[q].w += a.w;
      }
    }
  }
}

// ---------------------------------------------------------------------------
// K4: decode GEMM  out[t][v] = relu(W_dec[v,:] . h[t,:] + b_dec[v])
// Round-3 structure (coalesced LDS-staged W: FETCH 35MB, confirmed) with the
// scratch-spill bug fixed: ALL acc[] accesses are static (full unroll,
// including the output stores — round 3's `#pragma unroll 1` store loop
// demoted acc[101] to scratch: VGPR=84, WRITE_SIZE=150MB, 255us).
// Adds 2-stage prefetch of the h lane-registers across k.
// ---------------------------------------------------------------------------
__global__ __launch_bounds__(256, 1) void k_dec(
    const float* __restrict__ W_dec, const float* __restrict__ b_dec,
    const float* __restrict__ h_allT, float* __restrict__ out) {
  __shared__ float lds_w[32 * 256];  // [k][v] swizzled, 32 KB
  const int tid = threadIdx.x;
  const int lane = tid & 63;
  const int vb = blockIdx.x * 256;
  const int v = vb + tid;

  float acc[TROWS];
#pragma unroll
  for (int t = 0; t < TROWS; t++) acc[t] = 0.f;

  // prefetch h row k=0 into lane regs
  float vh0 = h_allT[0 * 104 + lane];
  float vh1 = h_allT[0 * 104 + 64 + lane];

  for (int kc = 0; kc < 8; kc++) {
    __syncthreads();  // protect LDS reuse
    // ---- stage W chunk [256 rows x 32 k], coalesced, transposed+swizzled ----
#pragma unroll
    for (int i = 0; i < 8; i++) {
      const int f = tid + i * 256;      // 0..2047
      const int row = f >> 3;           // 0..255
      const int cc = f & 7;             // float4 index within 32-k chunk
      int rg = vb + row;
      rg = rg < VOCAB ? rg : VOCAB - 1;
      const float4 wv = *(const float4*)(W_dec + rg * EMB + kc * 32 + cc * 4);
      const int k0 = cc * 4;
      lds_w[(k0 + 0) * 256 + (row ^ (((k0 + 0) & 15) << 2))] = wv.x;
      lds_w[(k0 + 1) * 256 + (row ^ (((k0 + 1) & 15) << 2))] = wv.y;
      lds_w[(k0 + 2) * 256 + (row ^ (((k0 + 2) & 15) << 2))] = wv.z;
      lds_w[(k0 + 3) * 256 + (row ^ (((k0 + 3) & 15) << 2))] = wv.w;
    }
    __syncthreads();

    // ---- compute: 32 k-steps, 101 fma each; h for k+1 prefetched ----
#pragma unroll 1
    for (int k = 0; k < 32; k++) {
      const int kn = kc * 32 + k + 1;
      float nvh0 = 0.f, nvh1 = 0.f;
      if (kn < 256) {
        nvh0 = h_allT[kn * 104 + lane];
        nvh1 = h_allT[kn * 104 + 64 + lane];
      }
      const float w = lds_w[k * 256 + (tid ^ ((k & 15) << 2))];
#pragma unroll
      for (int t = 0; t < TROWS; t++) {
        const float s = __uint_as_float(__builtin_amdgcn_readlane(
            __float_as_uint(t < 64 ? vh0 : vh1), t & 63));
        acc[t] = fmaf(s, w, acc[t]);
      }
      vh0 = nvh0;
      vh1 = nvh1;
    }
  }

  const int rc = v < VOCAB ? v : VOCAB - 1;
  const float bd = b_dec[rc];
  if (v < VOCAB) {
#pragma unroll
    for (int t = 0; t < TROWS; t++) {
      out[t * VOCAB + v] = fmaxf(acc[t] + bd, 0.f);  // static acc index
    }
  }
}

// ---------------------------------------------------------------------------
extern "C" void kernel_launch(void* const* d_in, const int* in_sizes, int n_in,
                              void* d_out, int out_size, void* d_ws, size_t ws_size,
                              hipStream_t stream) {
  const float* board  = (const float*)d_in[0];
  const float* conv_w = (const float*)d_in[1];
  const float* conv_b = (const float*)d_in[2];
  const float* bn_g   = (const float*)d_in[3];
  const float* bn_b   = (const float*)d_in[4];
  const float* p      = (const float*)d_in[5];
  const float* W_lin  = (const float*)d_in[6];
  const float* b_lin  = (const float*)d_in[7];
  const float* W_ih   = (const float*)d_in[8];
  const float* b_ih   = (const float*)d_in[9];
  const float* W_hh   = (const float*)d_in[10];
  const float* b_hh   = (const float*)d_in[11];
  const float* W_dec  = (const float*)d_in[12];
  const float* b_dec  = (const float*)d_in[13];

  float* wsf   = (float*)d_ws;
  float* feat  = wsf;                        // 256 floats
  float* d1g   = wsf + 256;                  // 384 slot (361 used)
  float* h_all = wsf + 640;                  // 104*256 floats
  unsigned long long* hcomm =
      (unsigned long long*)(wsf + 640 + 104 * 256);   // 512 u64 (8B aligned)
  float* h_allT = wsf + 640 + 104 * 256 + 1024;       // 256*104 floats
  unsigned long long* xtab =
      (unsigned long long*)(wsf + 640 + 104 * 256 + 1024 + 256 * 104);  // 32 u64
  // No workspace init needed: poison 0xAAAAAAAA never matches the tags
  // (hcomm: t+1 in [1,100]; xtab: 0xE1EC0000). h_allT pad t=101..103 unused.

  k_conv<<<1, 384, 0, stream>>>(board, conv_w, conv_b, bn_g, bn_b, p, d1g);
  k_feat<<<16, 256, 0, stream>>>(W_lin, b_lin, d1g, feat);
  k_lstm<<<NLB, 512, 0, stream>>>(W_ih, b_ih, W_hh, b_hh, feat, h_all, h_allT, hcomm, xtab);
  k_dec<<<(VOCAB + 255) / 256, 256, 0, stream>>>(W_dec, b_dec, h_allT, (float*)d_out);
}

// Round 5
// 414.702 us; speedup vs baseline: 9.2557x; 1.2312x over previous
//
#include <hip/hip_runtime.h>
#include <math.h>

#define EMB 256
#define VOCAB 50000
#define TROWS 101
#define NLB 32    // lstm candidate blocks (election among these; 4 winners)
#define NW 4      // lstm worker workgroups
#define NDECB 196 // decode blocks (196 x 256 vocab rows = 50176 >= 50000)
#define NTOT (NLB + NDECB)

__device__ __forceinline__ float sigf(float x) { return 1.0f / (1.0f + expf(-x)); }

// ---------------------------------------------------------------------------
// K1: conv tower (8 shared-weight conv3x3 + batchnorm stages), single block.
// ---------------------------------------------------------------------------
__global__ __launch_bounds__(384) void k_conv(
    const float* __restrict__ board, const float* __restrict__ conv_w,
    const float* __restrict__ conv_b, const float* __restrict__ bn_g,
    const float* __restrict__ bn_b, const float* __restrict__ p,
    float* __restrict__ d1g) {
  __shared__ float xa[361], xb[361];
  __shared__ float wred[6];
  __shared__ float mu_s, var_s;
  const int tid = threadIdx.x;
  const bool act = tid < 361;
  const int i = tid / 19, j = tid % 19;
  float cw[9];
#pragma unroll
  for (int q = 0; q < 9; q++) cw[q] = conv_w[q];
  const float cb = conv_b[0], gam = bn_g[0], bet = bn_b[0];
  if (act) xa[tid] = board[tid];
  __syncthreads();

  float d2 = 0.f;
  float* cur = xa;
  float* nxt = xb;
  for (int stage = 0; stage < 8; stage++) {
    float y = 0.f;
    if (act) {
#pragma unroll
      for (int di = 0; di < 3; di++) {
#pragma unroll
        for (int dj = 0; dj < 3; dj++) {
          int ii = i + di - 1, jj = j + dj - 1;
          float xv = (ii >= 0 && ii < 19 && jj >= 0 && jj < 19) ? cur[ii * 19 + jj] : 0.f;
          y += cw[di * 3 + dj] * xv;
        }
      }
      y += cb;
    }
    float s = act ? y : 0.f;
#pragma unroll
    for (int o = 32; o > 0; o >>= 1) s += __shfl_xor(s, o);
    if ((tid & 63) == 0) wred[tid >> 6] = s;
    __syncthreads();
    if (tid == 0) {
      float tt = 0.f;
      for (int q = 0; q < 6; q++) tt += wred[q];
      mu_s = tt / 361.f;
    }
    __syncthreads();
    const float mu = mu_s;
    float d = act ? (y - mu) : 0.f;
    s = d * d;
#pragma unroll
    for (int o = 32; o > 0; o >>= 1) s += __shfl_xor(s, o);
    if ((tid & 63) == 0) wred[tid >> 6] = s;
    __syncthreads();
    if (tid == 0) {
      float tt = 0.f;
      for (int q = 0; q < 6; q++) tt += wred[q];
      var_s = tt / 361.f;
    }
    __syncthreads();
    const float xn = gam * (y - mu) * (1.0f / sqrtf(var_s + 1e-5f)) + bet;

    float v;
    if (stage == 0) {
      v = fmaxf(p[0] * xn, 0.f);
      d2 = v;
    } else if (stage == 7) {
      v = fmaxf(xn, 0.f);
    } else if (stage & 1) {
      v = fmaxf(p[stage] * xn, 0.f);
    } else {
      v = fmaxf(p[stage] * xn + d2, 0.f);
      d2 = v;
    }
    if (act) nxt[tid] = v;
    __syncthreads();
    float* tmp = cur; cur = nxt; nxt = tmp;
  }
  if (act) d1g[tid] = cur[tid];
}

// ---------------------------------------------------------------------------
// K2: feat = W_lin @ d1 + b_lin.
// ---------------------------------------------------------------------------
__global__ __launch_bounds__(256) void k_feat(
    const float* __restrict__ W_lin, const float* __restrict__ b_lin,
    const float* __restrict__ d1g, float* __restrict__ feat) {
  const int wid = threadIdx.x >> 6, lane = threadIdx.x & 63;
  const int rbase = blockIdx.x * 16 + wid * 4;
  for (int rr = 0; rr < 4; rr++) {
    const int r = rbase + rr;
    const float* wrow = W_lin + r * 361;
    float s = 0.f;
    for (int k = lane; k < 361; k += 64) s += wrow[k] * d1g[k];
#pragma unroll
    for (int o = 32; o > 0; o >>= 1) s += __shfl_xor(s, o);
    if (lane == 0) feat[r] = s + b_lin[r];
  }
}

// ---------------------------------------------------------------------------
// K3 (fused): LSTM chain + streaming decode in ONE launch.
//  blocks 0..31   : lstm candidates -> election picks 4 same-XCD workers
//                   (proven round-0/4 hcomm agent-packet protocol for peers).
//  blocks 32..227 : 196 persistent decode blocks. Each holds 256 vocab rows'
//                   weights in VGPRs (2 threads/row, 128 cols each, one-time
//                   per-lane-sequential load). Per step t: wave 0 polls the
//                   4-flag line (release-published by producers, so payloads
//                   are MALL-visible once tags match), block barrier, all
//                   waves pull h[t] into 2 lane regs, readlane-dot, halves
//                   combined via LDS, relu-store out[t]. Decode work/step
//                   (~1us) < producer pace (~2.2us) => decode fully hidden.
// ---------------------------------------------------------------------------
__global__ __launch_bounds__(512) void k_net(
    const float* __restrict__ W_ih, const float* __restrict__ b_ih,
    const float* __restrict__ W_hh, const float* __restrict__ b_hh,
    const float* __restrict__ feat, const float* __restrict__ W_dec,
    const float* __restrict__ b_dec, unsigned long long* hcomm,
    unsigned long long* xtab, unsigned* hflag, unsigned* hdec,
    float* __restrict__ out) {
  __shared__ float h_lds[EMB];
  __shared__ float gbuf[2][EMB];
  __shared__ float pbuf[2][EMB];
  __shared__ int sxcd[NLB];
  const int tid = threadIdx.x;

  if (blockIdx.x >= NLB) {
    // ======================= decode role =======================
    const int db = blockIdx.x - NLB;          // 0..195
    const int w = tid >> 6, lane = tid & 63;
    const int sh = w & 1;                     // k-half owned: [sh*128, sh*128+128)
    const int rr = (w >> 1) * 64 + lane;      // row within tile 0..255
    const int v = db * 256 + rr;
    const int rv = v < VOCAB ? v : VOCAB - 1;
    float4 w4[32];                            // 128 weight cols in regs
    {
      const float4* wr = (const float4*)(W_dec + rv * EMB + sh * 128);
#pragma unroll
      for (int q = 0; q < 32; q++) w4[q] = wr[q];
    }
    const float bd = b_dec[rv];

    for (int t = 0; t < TROWS; t++) {
      if (w == 0) {  // only wave 0 polls the hot flag line (MALL hotspot ctrl)
        const unsigned want = (unsigned)(t + 1);
        while (1) {
          const unsigned f0 = __hip_atomic_load(&hflag[t * 4 + 0], __ATOMIC_RELAXED, __HIP_MEMORY_SCOPE_AGENT);
          const unsigned f1 = __hip_atomic_load(&hflag[t * 4 + 1], __ATOMIC_RELAXED, __HIP_MEMORY_SCOPE_AGENT);
          const unsigned f2 = __hip_atomic_load(&hflag[t * 4 + 2], __ATOMIC_RELAXED, __HIP_MEMORY_SCOPE_AGENT);
          const unsigned f3 = __hip_atomic_load(&hflag[t * 4 + 3], __ATOMIC_RELAXED, __HIP_MEMORY_SCOPE_AGENT);
          if (((f0 ^ want) | (f1 ^ want) | (f2 ^ want) | (f3 ^ want)) == 0u) break;
          __builtin_amdgcn_s_sleep(2);
        }
      }
      __syncthreads();  // B1: step-t payloads are MALL-visible for all waves

      // pull this thread's h-half into 2 lane regs (agent loads -> MALL)
      const float p0 = __uint_as_float(__hip_atomic_load(
          &hdec[t * EMB + sh * 128 + lane], __ATOMIC_RELAXED, __HIP_MEMORY_SCOPE_AGENT));
      const float p1 = __uint_as_float(__hip_atomic_load(
          &hdec[t * EMB + sh * 128 + 64 + lane], __ATOMIC_RELAXED, __HIP_MEMORY_SCOPE_AGENT));

      float a0 = 0.f, a1 = 0.f, a2 = 0.f, a3 = 0.f;
#pragma unroll
      for (int k = 0; k < 32; k++) {
        const float4 wv = w4[k];
        const int kk = 4 * k;
        const float s0 = __uint_as_float(__builtin_amdgcn_readlane(
            __float_as_uint(kk + 0 < 64 ? p0 : p1), (kk + 0) & 63));
        const float s1 = __uint_as_float(__builtin_amdgcn_readlane(
            __float_as_uint(kk + 1 < 64 ? p0 : p1), (kk + 1) & 63));
        const float s2 = __uint_as_float(__builtin_amdgcn_readlane(
            __float_as_uint(kk + 2 < 64 ? p0 : p1), (kk + 2) & 63));
        const float s3 = __uint_as_float(__builtin_amdgcn_readlane(
            __float_as_uint(kk + 3 < 64 ? p0 : p1), (kk + 3) & 63));
        a0 = fmaf(s0, wv.x, a0);
        a1 = fmaf(s1, wv.y, a1);
        a2 = fmaf(s2, wv.z, a2);
        a3 = fmaf(s3, wv.w, a3);
      }
      const float part = (a0 + a1) + (a2 + a3);
      if (sh) pbuf[t & 1][rr] = part;
      __syncthreads();  // B2: partials ready (parity dbuf makes reuse safe)
      if (!sh && v < VOCAB) {
        out[t * VOCAB + v] = fmaxf(part + pbuf[t & 1][rr] + bd, 0.f);
      }
    }
    return;
  }

  // ======================= lstm candidate role =======================
  // ---- same-XCD election (proven round-4 machinery) ----
  if (tid == 0) {
    unsigned xcc = __builtin_amdgcn_s_getreg(63508) & 7u;  // HW_REG_XCC_ID
    __hip_atomic_store(&xtab[blockIdx.x],
                       0xE1EC000000000000ULL | (unsigned long long)xcc,
                       __ATOMIC_RELAXED, __HIP_MEMORY_SCOPE_AGENT);
  }
  if (tid < NLB) {
    const unsigned long long* slot = &xtab[tid];
    unsigned long long u;
    while (1) {
      u = __hip_atomic_load(slot, __ATOMIC_RELAXED, __HIP_MEMORY_SCOPE_AGENT);
      if ((unsigned)(u >> 32) == 0xE1EC0000u) break;
      __builtin_amdgcn_s_sleep(2);
    }
    sxcd[tid] = (int)((unsigned)u & 7u);
  }
  __syncthreads();
  int target = -1;
  for (int x = 0; x < 8; x++) {
    int n = 0;
    for (int b = 0; b < NLB; b++) n += (sxcd[b] == x);
    if (n >= NW) { target = x; break; }
  }
  int rank = -1, seen = 0;
  for (int b = 0; b < NLB; b++) {
    if (sxcd[b] == target) {
      if (b == (int)blockIdx.x) rank = seen;
      seen++;
    }
  }
  if (rank < 0 || rank >= NW) return;  // losers exit, free their CUs
  const int g = rank;

  // ---- LSTM body (math identical to round 4) ----
  const int w = tid >> 6, lane = tid & 63;
  const int half = w & 1;
  const int gate = w >> 1;
  const int rloc = gate * 64 + lane;
  const int R = gate * 256 + g * 64 + lane;
  const float bsum = b_ih[R] + b_hh[R];

  float4 w4[32];
  {
    const float4* wih = (const float4*)(W_ih + R * EMB + half * 128);
#pragma unroll
    for (int q = 0; q < 32; q++) w4[q] = wih[q];
  }
  if (tid < EMB) h_lds[tid] = feat[tid];
  float c = 0.f;
  __syncthreads();

  for (int t = 0; t <= 100; t++) {
    const float hv0 = h_lds[half * 128 + lane];
    const float hv1 = h_lds[half * 128 + 64 + lane];

    float a0 = (half == 0) ? bsum : 0.f, a1 = 0.f, a2 = 0.f, a3 = 0.f;
#pragma unroll
    for (int k = 0; k < 32; k++) {
      const float4 wv = w4[k];
      const int kk = 4 * k;
      const float s0 = __uint_as_float(__builtin_amdgcn_readlane(
          __float_as_uint(kk + 0 < 64 ? hv0 : hv1), (kk + 0) & 63));
      const float s1 = __uint_as_float(__builtin_amdgcn_readlane(
          __float_as_uint(kk + 1 < 64 ? hv0 : hv1), (kk + 1) & 63));
      const float s2 = __uint_as_float(__builtin_amdgcn_readlane(
          __float_as_uint(kk + 2 < 64 ? hv0 : hv1), (kk + 2) & 63));
      const float s3 = __uint_as_float(__builtin_amdgcn_readlane(
          __float_as_uint(kk + 3 < 64 ? hv0 : hv1), (kk + 3) & 63));
      a0 = fmaf(s0, wv.x, a0);
      a1 = fmaf(s1, wv.y, a1);
      a2 = fmaf(s2, wv.z, a2);
      a3 = fmaf(s3, wv.w, a3);
    }
    gbuf[half][rloc] = (a0 + a1) + (a2 + a3);
    __syncthreads();  // B1: gbuf ready; h_lds reads of this step done

    if (tid < 64) {   // producer wave (one full wave)
      const float gi = gbuf[0][tid]       + gbuf[1][tid];
      const float gf = gbuf[0][64 + tid]  + gbuf[1][64 + tid];
      const float gg = gbuf[0][128 + tid] + gbuf[1][128 + tid];
      const float go = gbuf[0][192 + tid] + gbuf[1][192 + tid];
      c = sigf(gf) * c + sigf(gi) * tanhf(gg);
      const float h = sigf(go) * tanhf(c);
      const int j = g * 64 + tid;
      h_lds[j] = h;  // local fast path
      // payload for decode blocks (all steps incl. t=100)
      __hip_atomic_store(&hdec[t * EMB + j], __float_as_uint(h),
                         __ATOMIC_RELAXED, __HIP_MEMORY_SCOPE_AGENT);
      if (t < 100) {  // peer packet (proven protocol, unchanged)
        unsigned long long pkt =
            ((unsigned long long)(unsigned)(t + 1) << 32) | (unsigned long long)__float_as_uint(h);
        __hip_atomic_store(&hcomm[(t & 1) * EMB + j], pkt,
                           __ATOMIC_RELAXED, __HIP_MEMORY_SCOPE_AGENT);
      }
      if (tid == 0) {
        // RELEASE: wave-wide vmcnt(0) drains the 64 payload stores to the
        // coherence point before the flag becomes visible.
        __hip_atomic_store(&hflag[t * 4 + g], (unsigned)(t + 1),
                           __ATOMIC_RELEASE, __HIP_MEMORY_SCOPE_AGENT);
      }
    }
    if (t < 100) {
      if (tid < EMB && (tid < g * 64 || tid >= g * 64 + 64)) {  // remote slots
        const unsigned long long* slot = &hcomm[(t & 1) * EMB + tid];
        unsigned long long u;
        while (1) {
          u = __hip_atomic_load(slot, __ATOMIC_RELAXED, __HIP_MEMORY_SCOPE_AGENT);
          if ((unsigned)(u >> 32) == (unsigned)(t + 1)) break;
        }
        h_lds[tid] = __uint_as_float((unsigned)u);
      }
      __syncthreads();  // B2: h_lds(t+1) ready
    }
    if (t == 0) {  // switch to W_sum = W_ih + W_hh for steps >= 1
      const float4* whh = (const float4*)(W_hh + R * EMB + half * 128);
#pragma unroll
      for (int q = 0; q < 32; q++) {
        float4 a = whh[q];
        w4[q].x += a.x; w4[q].y += a.y; w4[q].z += a.z; w4[q].w += a.w;
      }
    }
  }
}

// ---------------------------------------------------------------------------
extern "C" void kernel_launch(void* const* d_in, const int* in_sizes, int n_in,
                              void* d_out, int out_size, void* d_ws, size_t ws_size,
                              hipStream_t stream) {
  const float* board  = (const float*)d_in[0];
  const float* conv_w = (const float*)d_in[1];
  const float* conv_b = (const float*)d_in[2];
  const float* bn_g   = (const float*)d_in[3];
  const float* bn_b   = (const float*)d_in[4];
  const float* p      = (const float*)d_in[5];
  const float* W_lin  = (const float*)d_in[6];
  const float* b_lin  = (const float*)d_in[7];
  const float* W_ih   = (const float*)d_in[8];
  const float* b_ih   = (const float*)d_in[9];
  const float* W_hh   = (const float*)d_in[10];
  const float* b_hh   = (const float*)d_in[11];
  const float* W_dec  = (const float*)d_in[12];
  const float* b_dec  = (const float*)d_in[13];

  float* wsf = (float*)d_ws;
  float* feat = wsf;                                   // 256 f
  float* d1g  = wsf + 256;                             // 384 f (361 used)
  unsigned long long* hcomm = (unsigned long long*)(wsf + 640);  // 512 u64
  unsigned long long* xtab  = hcomm + 512;             // 32 u64
  unsigned* hflag = (unsigned*)(xtab + 32);            // 512 u32 (404 used)
  unsigned* hdec  = hflag + 512;                       // 101*256 u32
  // No init needed: poison 0xAAAAAAAA never matches tags (hcomm: t+1 in
  // [1,100]; hflag: t+1 in [1,101]; xtab: 0xE1EC0000). hdec read post-flag.

  k_conv<<<1, 384, 0, stream>>>(board, conv_w, conv_b, bn_g, bn_b, p, d1g);
  k_feat<<<16, 256, 0, stream>>>(W_lin, b_lin, d1g, feat);
  k_net<<<NTOT, 512, 0, stream>>>(W_ih, b_ih, W_hh, b_hh, feat, W_dec, b_dec,
                                  hcomm, xtab, hflag, hdec, (float*)d_out);
}